// Round 1
// baseline (116.221 us; speedup 1.0000x reference)
//
#include <hip/hip_runtime.h>
#include <hip/hip_bf16.h>

// Problem constants (fixed by reference setup_inputs)
#define NTRAJ 8
#define NRES  500
#define NBINS 34
#define ICHUNKS 250        // i-chunks, 2 i-values per chunk (250*2 = 500)
#define OUT_ELEMS (NTRAJ*NRES*3)   // 12000

// Main kernel: grid (ICHUNKS, 2), block 256.
// thread -> one j; block -> 2 consecutive i values; accumulate out[t,j,:] over
// those i in registers; write one partial slab per block (or atomicAdd fallback).
__global__ __launch_bounds__(256)
void force_main(const float* __restrict__ cb,    // [NTRAJ][NRES][3]
                const float* __restrict__ gw,    // [NRES i][NRES j][NBINS]
                const float* __restrict__ cen,   // [NBINS]
                const float* __restrict__ sig,   // [NBINS]
                float* __restrict__ dst,         // partial [ICHUNKS][NTRAJ][NRES][3] or out
                int atomicMode)
{
    const int tid = threadIdx.x;
    const int j   = blockIdx.y * 256 + tid;
    const int ic  = blockIdx.x;
    if (j >= NRES) return;   // 12 idle lanes in jc=1 blocks; no barriers used

    // coords for this thread's j, all trajectories
    float cbj[NTRAJ][3];
#pragma unroll
    for (int t = 0; t < NTRAJ; ++t)
#pragma unroll
        for (int c = 0; c < 3; ++c)
            cbj[t][c] = cb[t * (NRES * 3) + j * 3 + c];

    float acc[NTRAJ][3];
#pragma unroll
    for (int t = 0; t < NTRAJ; ++t)
#pragma unroll
        for (int c = 0; c < 3; ++c)
            acc[t][c] = 0.0f;

#pragma unroll
    for (int ii = 0; ii < 2; ++ii) {
        const int i = ic * 2 + ii;

        float dx[NTRAJ], dy[NTRAJ], dz[NTRAJ], d[NTRAJ];
#pragma unroll
        for (int t = 0; t < NTRAJ; ++t) {
            // cb[t,i,:] is wave-uniform (i from blockIdx) -> scalar loads
            const float xi = cb[t * (NRES * 3) + i * 3 + 0];
            const float yi = cb[t * (NRES * 3) + i * 3 + 1];
            const float zi = cb[t * (NRES * 3) + i * 3 + 2];
            dx[t] = cbj[t][0] - xi;           // diffs = cb[t,j] - cb[t,i]
            dy[t] = cbj[t][1] - yi;
            dz[t] = cbj[t][2] - zi;
            float d2 = dx[t] * dx[t] + dy[t] * dy[t] + dz[t] * dz[t];
            float dd = sqrtf(d2);
            dd = fminf(fmaxf(dd, 0.1f), 40.0f);   // clip(., 0.1, FORCE_CUTOFF)
            d[t] = dd;
        }

        float force[NTRAJ];
#pragma unroll
        for (int t = 0; t < NTRAJ; ++t) force[t] = 0.0f;

        // gw row for (i, j): 34 contiguous floats, 8B-aligned -> float2 loads
        const float2* g2 = reinterpret_cast<const float2*>(
            gw + (size_t)i * (NRES * NBINS) + (size_t)j * NBINS);

#pragma unroll
        for (int k = 0; k < NBINS / 2; ++k) {
            const float2 wpair = g2[k];
#pragma unroll
            for (int u = 0; u < 2; ++u) {
                const int b   = 2 * k + u;
                const float w = u ? wpair.y : wpair.x;
                // per-bin constants (uniform across lanes and t)
                const float sv = __builtin_amdgcn_rcpf(sig[b]);   // 1/sigma
                const float s2 = sv * sv;                          // 1/sigma^2
                // exp(-0.5*(dfm/sig)^2) = exp2(dfm^2 * (-0.5*log2e/sig^2))
                const float c1 = s2 * -0.72134752044448f;          // -0.5*log2(e)*s2
                // force contrib = -dfm * (w / sig^3) * e
                const float wb = (w * sv) * s2;                    // w/sigma^3
                const float cc = cen[b];
#pragma unroll
                for (int t = 0; t < NTRAJ; ++t) {
                    const float dfm = d[t] - cc;
                    const float e   = __builtin_amdgcn_exp2f(dfm * dfm * c1);
                    force[t] = fmaf(-(dfm * wb), e, force[t]);
                }
            }
        }

        // pair_accs = -force * K * diffs / d ; accumulate over i
#pragma unroll
        for (int t = 0; t < NTRAJ; ++t) {
            const float s = (force[t] * __builtin_amdgcn_rcpf(d[t])) * -150.0f;
            acc[t][0] = fmaf(s, dx[t], acc[t][0]);
            acc[t][1] = fmaf(s, dy[t], acc[t][1]);
            acc[t][2] = fmaf(s, dz[t], acc[t][2]);
        }
    }

    if (atomicMode) {
#pragma unroll
        for (int t = 0; t < NTRAJ; ++t)
#pragma unroll
            for (int c = 0; c < 3; ++c)
                atomicAdd(dst + t * (NRES * 3) + j * 3 + c, acc[t][c]);
    } else {
        float* p = dst + (size_t)ic * OUT_ELEMS;
#pragma unroll
        for (int t = 0; t < NTRAJ; ++t)
#pragma unroll
            for (int c = 0; c < 3; ++c)
                p[t * (NRES * 3) + j * 3 + c] = acc[t][c];
    }
}

// Reduce partials: out[o] = sum_ic part[ic][o]; fully coalesced.
__global__ __launch_bounds__(256)
void reduce_k(const float* __restrict__ part, float* __restrict__ out)
{
    const int o = blockIdx.x * 256 + threadIdx.x;
    if (o >= OUT_ELEMS) return;
    float s = 0.0f;
#pragma unroll 5
    for (int ic = 0; ic < ICHUNKS; ++ic)
        s += part[(size_t)ic * OUT_ELEMS + o];
    out[o] = s;
}

__global__ __launch_bounds__(256)
void zero_k(float* __restrict__ out)
{
    const int o = blockIdx.x * 256 + threadIdx.x;
    if (o < OUT_ELEMS) out[o] = 0.0f;
}

extern "C" void kernel_launch(void* const* d_in, const int* in_sizes, int n_in,
                              void* d_out, int out_size, void* d_ws, size_t ws_size,
                              hipStream_t stream)
{
    const float* cb  = (const float*)d_in[0];   // coords_cb [8,500,3]
    const float* gw  = (const float*)d_in[1];   // gaussian_weights [500,500,34]
    const float* cen = (const float*)d_in[2];   // dist_bin_centres [34]
    const float* sig = (const float*)d_in[3];   // sigmas [34]
    float* out = (float*)d_out;                 // [8,500,3]

    const size_t need = (size_t)ICHUNKS * OUT_ELEMS * sizeof(float);  // 12 MB
    const int outBlocks = (OUT_ELEMS + 255) / 256;

    if (ws_size >= need) {
        float* part = (float*)d_ws;
        force_main<<<dim3(ICHUNKS, 2), 256, 0, stream>>>(cb, gw, cen, sig, part, 0);
        reduce_k<<<outBlocks, 256, 0, stream>>>(part, out);
    } else {
        zero_k<<<outBlocks, 256, 0, stream>>>(out);
        force_main<<<dim3(ICHUNKS, 2), 256, 0, stream>>>(cb, gw, cen, sig, out, 1);
    }
}

// Round 2
// 105.561 us; speedup vs baseline: 1.1010x; 1.1010x over previous
//
#include <hip/hip_runtime.h>

// Problem constants (fixed by reference setup_inputs)
#define NTRAJ 8
#define NRES  500
#define NBINS 34
#define NSLAB NRES                 // one partial slab per i value
#define OUT_ELEMS (NTRAJ*NRES*3)   // 12000
#define OUT4 (OUT_ELEMS/4)         // 3000 float4s
#define RED_G   10                 // slab groups in reduce
#define RED_PER (NSLAB/RED_G)      // 50 slabs per group

// Main kernel: grid (NSLAB, 2), block 256. thread -> one j; block -> one i.
// Accumulate out[t,j,:] contribution of this i in registers, write one
// partial slab per i. 1000 blocks = 4000 waves => ~4 waves/SIMD resident.
__global__ __launch_bounds__(256)
void force_main(const float* __restrict__ cb,    // [NTRAJ][NRES][3]
                const float* __restrict__ gw,    // [NRES i][NRES j][NBINS]
                const float* __restrict__ cen,   // [NBINS]
                const float* __restrict__ sig,   // [NBINS]
                float* __restrict__ part)        // [NSLAB][NTRAJ][NRES][3]
{
    const int tid = threadIdx.x;
    const int j   = blockIdx.y * 256 + tid;
    const int i   = blockIdx.x;
    if (j >= NRES) return;   // 12 idle lanes in y=1 blocks; no barriers used

    // coords for this thread's j, all trajectories
    float cbj[NTRAJ][3];
#pragma unroll
    for (int t = 0; t < NTRAJ; ++t)
#pragma unroll
        for (int c = 0; c < 3; ++c)
            cbj[t][c] = cb[t * (NRES * 3) + j * 3 + c];

    float dx[NTRAJ], dy[NTRAJ], dz[NTRAJ], d[NTRAJ];
#pragma unroll
    for (int t = 0; t < NTRAJ; ++t) {
        // cb[t,i,:] is wave-uniform (i from blockIdx) -> scalar loads
        const float xi = cb[t * (NRES * 3) + i * 3 + 0];
        const float yi = cb[t * (NRES * 3) + i * 3 + 1];
        const float zi = cb[t * (NRES * 3) + i * 3 + 2];
        dx[t] = cbj[t][0] - xi;            // diffs = cb[t,j] - cb[t,i]
        dy[t] = cbj[t][1] - yi;
        dz[t] = cbj[t][2] - zi;
        float d2 = dx[t] * dx[t] + dy[t] * dy[t] + dz[t] * dz[t];
        float dd = sqrtf(d2);
        d[t] = fminf(fmaxf(dd, 0.1f), 40.0f);   // clip(., 0.1, FORCE_CUTOFF)
    }

    float force[NTRAJ];
#pragma unroll
    for (int t = 0; t < NTRAJ; ++t) force[t] = 0.0f;

    // gw row for (i, j): 34 contiguous floats, 8B-aligned -> float2 loads
    const float2* g2 = reinterpret_cast<const float2*>(
        gw + (size_t)i * (NRES * NBINS) + (size_t)j * NBINS);

#pragma unroll
    for (int k = 0; k < NBINS / 2; ++k) {
        const float2 wpair = g2[k];
#pragma unroll
        for (int u = 0; u < 2; ++u) {
            const int b   = 2 * k + u;
            const float w = u ? wpair.y : wpair.x;
            // per-bin constants (lane-uniform; full unroll -> scalar loads)
            const float sv = __builtin_amdgcn_rcpf(sig[b]);    // 1/sigma
            const float s2 = sv * sv;                          // 1/sigma^2
            // exp(-0.5*(dfm/sig)^2) = exp2(dfm^2 * (-0.5*log2(e)/sig^2))
            const float c1 = s2 * -0.72134752044448f;
            // force contrib = -dfm * (w / sig^3) * e
            const float wb = (w * sv) * s2;                    // w/sigma^3 (per-lane)
            const float cc = cen[b];
#pragma unroll
            for (int t = 0; t < NTRAJ; ++t) {
                const float dfm = d[t] - cc;
                const float e   = __builtin_amdgcn_exp2f((dfm * c1) * dfm);
                force[t] = fmaf(-(dfm * wb), e, force[t]);
            }
        }
    }

    // pair_accs = -force * K * diffs / d ; write this i's slab
    float* p = part + (size_t)i * OUT_ELEMS;
#pragma unroll
    for (int t = 0; t < NTRAJ; ++t) {
        const float s = (force[t] * __builtin_amdgcn_rcpf(d[t])) * -150.0f;
        p[t * (NRES * 3) + j * 3 + 0] = s * dx[t];
        p[t * (NRES * 3) + j * 3 + 1] = s * dy[t];
        p[t * (NRES * 3) + j * 3 + 2] = s * dz[t];
    }
}

// Reduce partials: grid (12, RED_G), block 256. Each thread sums one float4
// across RED_PER slabs, then 4 atomicAdds into out (10-way contention only).
__global__ __launch_bounds__(256)
void reduce_k(const float* __restrict__ part, float* __restrict__ out)
{
    const int f = blockIdx.x * 256 + threadIdx.x;   // float4 index
    if (f >= OUT4) return;
    const int g = blockIdx.y;

    const float4* p4 = reinterpret_cast<const float4*>(part);
    float4 s = make_float4(0.f, 0.f, 0.f, 0.f);
#pragma unroll 10
    for (int ic = g * RED_PER; ic < (g + 1) * RED_PER; ++ic) {
        const float4 v = p4[(size_t)ic * OUT4 + f];
        s.x += v.x; s.y += v.y; s.z += v.z; s.w += v.w;
    }
    atomicAdd(out + f * 4 + 0, s.x);
    atomicAdd(out + f * 4 + 1, s.y);
    atomicAdd(out + f * 4 + 2, s.z);
    atomicAdd(out + f * 4 + 3, s.w);
}

extern "C" void kernel_launch(void* const* d_in, const int* in_sizes, int n_in,
                              void* d_out, int out_size, void* d_ws, size_t ws_size,
                              hipStream_t stream)
{
    const float* cb  = (const float*)d_in[0];   // coords_cb [8,500,3]
    const float* gw  = (const float*)d_in[1];   // gaussian_weights [500,500,34]
    const float* cen = (const float*)d_in[2];   // dist_bin_centres [34]
    const float* sig = (const float*)d_in[3];   // sigmas [34]
    float* out  = (float*)d_out;                // [8,500,3]
    float* part = (float*)d_ws;                 // 500 slabs * 12000 floats = 24 MB

    // zero the output (harness poisons it to 0xAA before every launch)
    hipMemsetAsync(out, 0, (size_t)OUT_ELEMS * sizeof(float), stream);

    force_main<<<dim3(NSLAB, 2), 256, 0, stream>>>(cb, gw, cen, sig, part);
    reduce_k<<<dim3((OUT4 + 255) / 256, RED_G), 256, 0, stream>>>(part, out);
}